// Round 6
// baseline (236.156 us; speedup 1.0000x reference)
//
#include <hip/hip_runtime.h>

#define T_SEQ 4096
#define DIM   64
#define NQT   32     // T / 128 (q tiles)
#define QTILE 128
#define NBH   32     // B*H
#define NCHUNK_TOT 80   // sum over qt of ceil((qt+1)/8)  (chunk = 16 kv-tiles of 64)

typedef __attribute__((ext_vector_type(8)))  short bhalf8;
typedef __attribute__((ext_vector_type(16))) float floatx16;

#if __has_builtin(__builtin_amdgcn_exp2f)
#define EXP2F(x) __builtin_amdgcn_exp2f(x)
#else
#define EXP2F(x) exp2f(x)
#endif

// sigma: swap bits 2<->3 (kv permutation matching MFMA C->B register order)
__device__ __forceinline__ int sig23(int s) {
  return (s & ~12) | ((s & 4) << 1) | ((s & 8) >> 1);
}

// pack two fp32 -> two bf16 in one inst; low = a, high = b
__device__ __forceinline__ unsigned pk2bf(float a, float b) {
  unsigned ua = __builtin_bit_cast(unsigned, a) + 0x8000u;
  unsigned ub = __builtin_bit_cast(unsigned, b) + 0x8000u;
  return __builtin_amdgcn_perm(ub, ua, 0x07060302u);
}
#if __has_builtin(__builtin_amdgcn_cvt_pk_bf16_f32)
typedef __attribute__((ext_vector_type(2))) __bf16 bf16x2_t;
__device__ __forceinline__ unsigned cvtpk(float a, float b) {
  return __builtin_bit_cast(unsigned, __builtin_amdgcn_cvt_pk_bf16_f32(a, b));
}
#else
__device__ __forceinline__ unsigned cvtpk(float a, float b) { return pk2bf(a, b); }
#endif

__device__ __forceinline__ float bflo(unsigned u) {
  return __builtin_bit_cast(float, u << 16);
}
__device__ __forceinline__ float bfhi(unsigned u) {
  return __builtin_bit_cast(float, u & 0xffff0000u);
}

union FragU { unsigned u[4]; bhalf8 v; };

__device__ __forceinline__ void gload_lds16(const void* g, void* l) {
#if __has_builtin(__builtin_amdgcn_global_load_lds)
  __builtin_amdgcn_global_load_lds(
      (const __attribute__((address_space(1))) unsigned*)g,
      (__attribute__((address_space(3))) unsigned*)l, 16, 0, 0);
#else
  *(uint4*)l = *(const uint4*)g;
#endif
}

// ---------------- prep: fp32 K/V -> bf16 swizzled 64-kv tiles in ws ----------
// Tile = 64 kv x 64 d (8KB bf16). K row-major per kv; V^T row d, sigma-permuted
// kv slots. One block preps 128 kv (2 tiles) for one bh.
__global__ __launch_bounds__(256, 2) void fa_prep(
    const float* __restrict__ K, const float* __restrict__ V,
    unsigned short* __restrict__ Kb, unsigned short* __restrict__ Vb) {
  const int tid = threadIdx.x;
  const int bid = blockIdx.x;
  const int bh = bid >> 5, kt = bid & 31;
  __shared__ __align__(16) unsigned short SS[16384];  // K tiles [0,8192), V tiles [8192,16384)
  __shared__ __align__(16) float VS[128 * 68];        // fp32 V tile, padded stride 68
  const int base = bh * (T_SEQ * DIM) + kt * (128 * DIM);

  // K: row kv, 8 chunks of 8 bf16, chunk swizzle c' = c ^ (kvl&7)
  {
    const float4* kp4 = reinterpret_cast<const float4*>(K + base);
    float4 kx[8];
#pragma unroll
    for (int c = 0; c < 8; ++c) kx[c] = kp4[tid + 256 * c];
#pragma unroll
    for (int c = 0; c < 8; ++c) {
      int f4 = tid + 256 * c;
      int kv = f4 >> 4;            // 0..127
      int d0 = (f4 & 15) << 2;
      unsigned lo = pk2bf(kx[c].x, kx[c].y);
      unsigned hi = pk2bf(kx[c].z, kx[c].w);
      unsigned long long u64 = (unsigned long long)lo | ((unsigned long long)hi << 32);
      int jt = kv >> 6, kvl = kv & 63;
      int idx = jt * 4096 + (kvl << 6) + ((((d0 >> 3) ^ (kvl & 7)) << 3) | (d0 & 7));
      *reinterpret_cast<unsigned long long*>(&SS[idx]) = u64;
    }
  }
  // V: coalesced load into fp32 LDS transpose buffer
  {
    const float4* vp4 = reinterpret_cast<const float4*>(V + base);
#pragma unroll
    for (int c = 0; c < 8; ++c) {
      float4 x = vp4[tid + 256 * c];
      int f4 = tid + 256 * c;
      int kv = f4 >> 4;
      int d0 = (f4 & 15) << 2;
      *reinterpret_cast<float4*>(&VS[kv * 68 + d0]) = x;
    }
  }
  __syncthreads();
  // pack V^T tiles: slot pair (s0,s0+1) <- kv (sig23), 8-chunk swizzle by d&7
  {
    const int s0 = (tid & 63) << 1;        // global slot 0..126 even
    const int db = (tid >> 6) << 4;        // d base
    const int jt = s0 >> 6, sl = s0 & 63;
    const int kva = jt * 64 + sig23(sl);
    const int kvb = kva + 1;
    float4 va[4], vb[4];
#pragma unroll
    for (int sg = 0; sg < 4; ++sg) {
      va[sg] = *reinterpret_cast<const float4*>(&VS[kva * 68 + db + 4 * sg]);
      vb[sg] = *reinterpret_cast<const float4*>(&VS[kvb * 68 + db + 4 * sg]);
    }
    const float* vaf = reinterpret_cast<const float*>(va);
    const float* vbf = reinterpret_cast<const float*>(vb);
#pragma unroll
    for (int j = 0; j < 16; ++j) {
      int d = db + j;
      unsigned u = pk2bf(vaf[j], vbf[j]);  // low = slot s0, high = s0+1
      int idx = 8192 + jt * 4096 + (d << 6) + ((((sl >> 3) ^ (d & 7)) << 3) | (sl & 7));
      *reinterpret_cast<unsigned*>(&SS[idx]) = u;
    }
  }
  __syncthreads();
  // linear dump (coalesced uint4); two 8KB tiles are consecutive
  const uint4* S4 = reinterpret_cast<const uint4*>(SS);
  uint4* KbT = reinterpret_cast<uint4*>(Kb + (size_t)(bh * 32 + kt) * 8192);
  uint4* VbT = reinterpret_cast<uint4*>(Vb + (size_t)(bh * 32 + kt) * 8192);
#pragma unroll
  for (int i = 0; i < 4; ++i) KbT[tid + 256 * i] = S4[tid + 256 * i];
#pragma unroll
  for (int i = 0; i < 4; ++i) VbT[tid + 256 * i] = S4[1024 + tid + 256 * i];
}

// ---------------- main: one block per (bh, qt, chunk-of-16 kv64-tiles) -------
__global__ __launch_bounds__(256, 4) void fa_main(
    const float* __restrict__ Q, const unsigned short* __restrict__ Kb,
    const unsigned short* __restrict__ Vb,
    unsigned short* __restrict__ Op, float* __restrict__ ML) {
  const int tid  = threadIdx.x;
  const int w    = tid >> 6;
  const int lane = tid & 63;
  const int n    = lane & 31;
  const int h    = lane >> 5;
  const int bid  = blockIdx.x;
  const int bh   = bid & (NBH - 1);
  const int f    = (NCHUNK_TOT - 1) - (bid >> 5);   // heavy chunks first

  int qt, ch;
  if (f < 8)       { qt = f;                         ch = 0; }
  else if (f < 24) { int g = f - 8;  qt = 8  + (g >> 1); ch = g & 1; }
  else if (f < 48) { int g = f - 24; int q3 = g / 3; qt = 16 + q3; ch = g - 3 * q3; }
  else             { int g = f - 48; qt = 24 + (g >> 2); ch = g & 3; }

  const int k0   = ch << 4;                 // in 64-kv tiles
  const int kend = min(k0 + 16, 2 * qt + 2);
  const int base = bh * (T_SEQ * DIM);

  __shared__ __align__(16) unsigned short Kl[4096];  // 64 kv x 64 d
  __shared__ __align__(16) unsigned short Vt[4096];  // 64 d x 64 slots

  const int qrow = qt * QTILE + w * 32 + n;
  const float cs = 0.125f * 1.44269504088896340736f;
  FragU qf[4];
  {
    const float* qp = Q + base + qrow * DIM + h * 8;
#pragma unroll
    for (int ks = 0; ks < 4; ++ks) {
      float4 a = *reinterpret_cast<const float4*>(qp + 16 * ks);
      float4 b = *reinterpret_cast<const float4*>(qp + 16 * ks + 4);
      qf[ks].u[0] = cvtpk(a.x * cs, a.y * cs);
      qf[ks].u[1] = cvtpk(a.z * cs, a.w * cs);
      qf[ks].u[2] = cvtpk(b.x * cs, b.y * cs);
      qf[ks].u[3] = cvtpk(b.z * cs, b.w * cs);
    }
  }

  floatx16 o0, o1, zc;
#pragma unroll
  for (int i = 0; i < 16; ++i) { o0[i] = 0.f; o1[i] = 0.f; zc[i] = 0.f; }
  float s_run = 0.f;

  const int soff = w * 2048 + lane * 16;    // byte offset this lane stages (8KB region)
  const char* kb0 = reinterpret_cast<const char*>(Kb) + (size_t)(bh * 64) * 8192;
  const char* vb0 = reinterpret_cast<const char*>(Vb) + (size_t)(bh * 64) * 8192;

  for (int kt = k0; kt < kend; ++kt) {
    __syncthreads();
    {
      const char* kb = kb0 + (size_t)kt * 8192;
      const char* vb = vb0 + (size_t)kt * 8192;
      char* kl = reinterpret_cast<char*>(Kl);
      char* vl = reinterpret_cast<char*>(Vt);
      gload_lds16(kb + soff,        kl + soff);
      gload_lds16(kb + soff + 1024, kl + soff + 1024);
      gload_lds16(vb + soff,        vl + soff);
      gload_lds16(vb + soff + 1024, vl + soff + 1024);
    }
    __syncthreads();

    float psum = 0.f;
#pragma unroll
    for (int tt = 0; tt < 2; ++tt) {
      // S^T strip = K[32tt..32tt+32) * Q^T
      floatx16 st;
      {
        const bhalf8 k0f = *reinterpret_cast<const bhalf8*>(
            &Kl[((32 * tt + n) << 6) | (((0 + h) ^ (n & 7)) << 3)]);
        st = __builtin_amdgcn_mfma_f32_32x32x16_bf16(k0f, qf[0].v, zc, 0, 0, 0);
#pragma unroll
        for (int ks = 1; ks < 4; ++ks) {
          const bhalf8 kfr = *reinterpret_cast<const bhalf8*>(
              &Kl[((32 * tt + n) << 6) | (((2 * ks + h) ^ (n & 7)) << 3)]);
          st = __builtin_amdgcn_mfma_f32_32x32x16_bf16(kfr, qf[ks].v, st, 0, 0, 0);
        }
      }

      if (kt >= 2 * qt) {  // diagonal 64-kv tiles: causal mask
        const int lim = (w << 5) + n - ((kt - 2 * qt) << 6);
#pragma unroll
        for (int r = 0; r < 16; ++r) {
          int kvl = 32 * tt + (r & 3) + 8 * (r >> 2) + 4 * h;
          st[r] = (kvl > lim) ? -__builtin_inff() : st[r];
        }
      }

      // p = exp2(score), accumulate row-sum
#pragma unroll
      for (int r = 0; r < 16; ++r) {
        float p = EXP2F(st[r]);
        st[r] = p;
        psum += p;
      }

      // raw C-layout regs -> B fragments (V sigma-permuted)
      FragU b0, b1;
      b0.u[0] = cvtpk(st[0],  st[1]);
      b0.u[1] = cvtpk(st[2],  st[3]);
      b0.u[2] = cvtpk(st[4],  st[5]);
      b0.u[3] = cvtpk(st[6],  st[7]);
      b1.u[0] = cvtpk(st[8],  st[9]);
      b1.u[1] = cvtpk(st[10], st[11]);
      b1.u[2] = cvtpk(st[12], st[13]);
      b1.u[3] = cvtpk(st[14], st[15]);

      const int sw = n & 7;
      const bhalf8 v00 = *reinterpret_cast<const bhalf8*>(
          &Vt[(n << 6) | (((4 * tt + 0 + h) ^ sw) << 3)]);
      const bhalf8 v01 = *reinterpret_cast<const bhalf8*>(
          &Vt[(n << 6) | (((4 * tt + 2 + h) ^ sw) << 3)]);
      const bhalf8 v10 = *reinterpret_cast<const bhalf8*>(
          &Vt[((32 + n) << 6) | (((4 * tt + 0 + h) ^ sw) << 3)]);
      const bhalf8 v11 = *reinterpret_cast<const bhalf8*>(
          &Vt[((32 + n) << 6) | (((4 * tt + 2 + h) ^ sw) << 3)]);
      o0 = __builtin_amdgcn_mfma_f32_32x32x16_bf16(v00, b0.v, o0, 0, 0, 0);
      o0 = __builtin_amdgcn_mfma_f32_32x32x16_bf16(v01, b1.v, o0, 0, 0, 0);
      o1 = __builtin_amdgcn_mfma_f32_32x32x16_bf16(v10, b0.v, o1, 0, 0, 0);
      o1 = __builtin_amdgcn_mfma_f32_32x32x16_bf16(v11, b1.v, o1, 0, 0, 0);
    }
    psum += __shfl_xor(psum, 32, 64);
    s_run += psum;
  }

  // partial epilogue: unnormalized bf16 O + l
  const int pidx = (((bh << 5) | qt) << 2) | ch;
  unsigned* opr = reinterpret_cast<unsigned*>(Op) + (size_t)pidx * 4096 + (w * 32 + n) * 32;
#pragma unroll
  for (int g = 0; g < 4; ++g) {
    opr[4 * g + 2 * h]          = cvtpk(o0[4 * g],     o0[4 * g + 1]);
    opr[4 * g + 2 * h + 1]      = cvtpk(o0[4 * g + 2], o0[4 * g + 3]);
    opr[16 + 4 * g + 2 * h]     = cvtpk(o1[4 * g],     o1[4 * g + 1]);
    opr[16 + 4 * g + 2 * h + 1] = cvtpk(o1[4 * g + 2], o1[4 * g + 3]);
  }
  if (h == 0) ML[(pidx << 7) + w * 32 + n] = s_run;
}

// ---------------- combine: O = sum(acc) / sum(l) over <=4 chunks -------------
__global__ __launch_bounds__(256, 2) void fa_combine(
    const unsigned short* __restrict__ Op, const float* __restrict__ ML,
    float* __restrict__ O) {
  const int bid = blockIdx.x;
  const int bh = bid >> 5, qt = bid & 31;
  const int nch = (qt >> 3) + 1;
  const int t = threadIdx.x;
  const int r = t >> 1, half = t & 1;
  const int pbase = ((bh << 5) | qt) << 2;

  float L = 0.f;
  for (int i = 0; i < nch; ++i) L += ML[((pbase + i) << 7) + r];

  float acc[32];
#pragma unroll
  for (int j = 0; j < 32; ++j) acc[j] = 0.f;

  for (int i = 0; i < nch; ++i) {
    const uint4* p = reinterpret_cast<const uint4*>(
        Op + (size_t)(pbase + i) * 8192 + r * 64 + 32 * half);
    uint4 q4[4];
#pragma unroll
    for (int j = 0; j < 4; ++j) q4[j] = p[j];
    const unsigned* u = reinterpret_cast<const unsigned*>(q4);
#pragma unroll
    for (int j = 0; j < 16; ++j) {
      acc[2 * j]     += bflo(u[j]);
      acc[2 * j + 1] += bfhi(u[j]);
    }
  }
  const float inv = 1.0f / L;
  float* op = O + (size_t)bh * (T_SEQ * DIM) + (size_t)(qt * 128 + r) * DIM + 32 * half;
#pragma unroll
  for (int g = 0; g < 8; ++g) {
    float4 x;
    x.x = acc[4 * g] * inv;  x.y = acc[4 * g + 1] * inv;
    x.z = acc[4 * g + 2] * inv;  x.w = acc[4 * g + 3] * inv;
    *reinterpret_cast<float4*>(op + 4 * g) = x;
  }
}

// ---------------- fallback (monolithic, 128-kv tiles, sigma-permuted V) ------
__global__ __launch_bounds__(256, 2) void fa_mono(
    const float* __restrict__ Q, const float* __restrict__ K,
    const float* __restrict__ V, float* __restrict__ O) {
  const int tid  = threadIdx.x;
  const int w    = tid >> 6;
  const int lane = tid & 63;
  const int n    = lane & 31;
  const int h    = lane >> 5;
  const int bid  = blockIdx.x;
  const int bh   = bid & (NBH - 1);
  const int qt   = (NQT - 1) - (bid >> 5);

  const int base = bh * (T_SEQ * DIM);
  __shared__ __align__(16) unsigned short Kl[128 * DIM];
  __shared__ __align__(16) unsigned short Vt[DIM * 128];

  const int qrow = qt * QTILE + w * 32 + n;
  const float cs = 0.125f * 1.44269504088896340736f;
  FragU qf[4];
  {
    const float* qp = Q + base + qrow * DIM + h * 8;
#pragma unroll
    for (int ks = 0; ks < 4; ++ks) {
      float4 a = *reinterpret_cast<const float4*>(qp + 16 * ks);
      float4 b = *reinterpret_cast<const float4*>(qp + 16 * ks + 4);
      qf[ks].u[0] = pk2bf(a.x * cs, a.y * cs);
      qf[ks].u[1] = pk2bf(a.z * cs, a.w * cs);
      qf[ks].u[2] = pk2bf(b.x * cs, b.y * cs);
      qf[ks].u[3] = pk2bf(b.z * cs, b.w * cs);
    }
  }

  floatx16 o0, o1;
#pragma unroll
  for (int i = 0; i < 16; ++i) { o0[i] = 0.f; o1[i] = 0.f; }
  float s_run = 0.f;

  for (int kt = 0; kt <= qt; ++kt) {
    __syncthreads();
    {
      const float4* kp4 = reinterpret_cast<const float4*>(K + base + kt * (128 * DIM));
      float4 kx[8];
#pragma unroll
      for (int c = 0; c < 8; ++c) kx[c] = kp4[tid + 256 * c];
#pragma unroll
      for (int c = 0; c < 8; ++c) {
        int f4 = tid + 256 * c;
        int kv = f4 >> 4;
        int d0 = (f4 & 15) << 2;
        unsigned lo = pk2bf(kx[c].x, kx[c].y);
        unsigned hi = pk2bf(kx[c].z, kx[c].w);
        unsigned long long u64 = (unsigned long long)lo | ((unsigned long long)hi << 32);
        int idx = (kv << 6) | ((((d0 >> 3) ^ (kv & 7)) << 3) | (d0 & 7));
        *reinterpret_cast<unsigned long long*>(&Kl[idx]) = u64;
      }
      const int s0 = (tid & 63) << 1;
      const int db = (tid >> 6) << 4;
      const int kva = sig23(s0);
      const float* vr0 = V + base + kt * (128 * DIM) + kva * DIM + db;
      const float* vr1 = vr0 + DIM;
      float4 va[4], vb[4];
#pragma unroll
      for (int sg = 0; sg < 4; ++sg) {
        va[sg] = *reinterpret_cast<const float4*>(vr0 + 4 * sg);
        vb[sg] = *reinterpret_cast<const float4*>(vr1 + 4 * sg);
      }
      const float* vaf = reinterpret_cast<const float*>(va);
      const float* vbf = reinterpret_cast<const float*>(vb);
#pragma unroll
      for (int j = 0; j < 16; ++j) {
        int d = db + j;
        unsigned u = pk2bf(vaf[j], vbf[j]);
        int idx = (d << 7) | ((((s0 >> 3) ^ (d & 15)) << 3) | (s0 & 7));
        *reinterpret_cast<unsigned*>(&Vt[idx]) = u;
      }
    }
    __syncthreads();

    floatx16 st[4];
#pragma unroll
    for (int tt = 0; tt < 4; ++tt) {
      floatx16 acc;
#pragma unroll
      for (int i = 0; i < 16; ++i) acc[i] = 0.f;
#pragma unroll
      for (int ks = 0; ks < 4; ++ks) {
        const bhalf8 kfrag = *reinterpret_cast<const bhalf8*>(
            &Kl[((32 * tt + n) << 6) | (((2 * ks + h) ^ (n & 7)) << 3)]);
        acc = __builtin_amdgcn_mfma_f32_32x32x16_bf16(kfrag, qf[ks].v, acc, 0, 0, 0);
      }
      st[tt] = acc;
    }

    if (kt == qt) {
#pragma unroll
      for (int tt = 0; tt < 4; ++tt)
#pragma unroll
        for (int r = 0; r < 16; ++r) {
          int kvloc = 32 * tt + (r & 3) + 8 * (r >> 2) + 4 * h;
          st[tt][r] = (kvloc > 32 * w + n) ? -__builtin_inff() : st[tt][r];
        }
    }

    float psum = 0.f;
#pragma unroll
    for (int tt = 0; tt < 4; ++tt)
#pragma unroll
      for (int r = 0; r < 16; ++r) {
        float p = EXP2F(st[tt][r]);
        st[tt][r] = p;
        psum += p;
      }
    psum += __shfl_xor(psum, 32, 64);
    s_run += psum;

#pragma unroll
    for (int tt = 0; tt < 4; ++tt) {
      FragU b0, b1;
      b0.u[0] = pk2bf(st[tt][0],  st[tt][1]);
      b0.u[1] = pk2bf(st[tt][2],  st[tt][3]);
      b0.u[2] = pk2bf(st[tt][4],  st[tt][5]);
      b0.u[3] = pk2bf(st[tt][6],  st[tt][7]);
      b1.u[0] = pk2bf(st[tt][8],  st[tt][9]);
      b1.u[1] = pk2bf(st[tt][10], st[tt][11]);
      b1.u[2] = pk2bf(st[tt][12], st[tt][13]);
      b1.u[3] = pk2bf(st[tt][14], st[tt][15]);

      const int sw = n & 15;
      const bhalf8 v00 = *reinterpret_cast<const bhalf8*>(
          &Vt[(n << 7) | (((4 * tt + 0 + h) ^ sw) << 3)]);
      const bhalf8 v01 = *reinterpret_cast<const bhalf8*>(
          &Vt[(n << 7) | (((4 * tt + 2 + h) ^ sw) << 3)]);
      const bhalf8 v10 = *reinterpret_cast<const bhalf8*>(
          &Vt[((32 + n) << 7) | (((4 * tt + 0 + h) ^ sw) << 3)]);
      const bhalf8 v11 = *reinterpret_cast<const bhalf8*>(
          &Vt[((32 + n) << 7) | (((4 * tt + 2 + h) ^ sw) << 3)]);
      o0 = __builtin_amdgcn_mfma_f32_32x32x16_bf16(v00, b0.v, o0, 0, 0, 0);
      o0 = __builtin_amdgcn_mfma_f32_32x32x16_bf16(v01, b1.v, o0, 0, 0, 0);
      o1 = __builtin_amdgcn_mfma_f32_32x32x16_bf16(v10, b0.v, o1, 0, 0, 0);
      o1 = __builtin_amdgcn_mfma_f32_32x32x16_bf16(v11, b1.v, o1, 0, 0, 0);
    }
  }

  const float inv = 1.0f / s_run;
  float* op = O + base + qrow * DIM;
#pragma unroll
  for (int g = 0; g < 4; ++g) {
    float4 x, y;
    x.x = o0[4 * g] * inv;  x.y = o0[4 * g + 1] * inv;
    x.z = o0[4 * g + 2] * inv;  x.w = o0[4 * g + 3] * inv;
    y.x = o1[4 * g] * inv;  y.y = o1[4 * g + 1] * inv;
    y.z = o1[4 * g + 2] * inv;  y.w = o1[4 * g + 3] * inv;
    *reinterpret_cast<float4*>(op + 8 * g + 4 * h)      = x;
    *reinterpret_cast<float4*>(op + 32 + 8 * g + 4 * h) = y;
  }
}

extern "C" void kernel_launch(void* const* d_in, const int* in_sizes, int n_in,
                              void* d_out, int out_size, void* d_ws, size_t ws_size,
                              hipStream_t stream) {
  (void)in_sizes; (void)n_in; (void)out_size;
  const float* Q = (const float*)d_in[0];
  const float* K = (const float*)d_in[1];
  const float* V = (const float*)d_in[2];
  float* O = (float*)d_out;

  // ws layout (bytes): Kb[16MB] | Vb[16MB] | Op[64MB bf16] | ML[2MB]
  const size_t OFF_KB = 0;
  const size_t OFF_VB = 16777216;
  const size_t OFF_OP = 33554432;
  const size_t OFF_ML = 100663296;
  const size_t NEED   = 102760448;

  if (ws_size >= NEED) {
    unsigned short* Kb = (unsigned short*)((char*)d_ws + OFF_KB);
    unsigned short* Vb = (unsigned short*)((char*)d_ws + OFF_VB);
    unsigned short* Op = (unsigned short*)((char*)d_ws + OFF_OP);
    float*          ML = (float*)((char*)d_ws + OFF_ML);
    fa_prep<<<dim3(NBH * NQT), dim3(256), 0, stream>>>(K, V, Kb, Vb);
    fa_main<<<dim3(NBH * NCHUNK_TOT), dim3(256), 0, stream>>>(Q, Kb, Vb, Op, ML);
    fa_combine<<<dim3(NBH * NQT), dim3(256), 0, stream>>>(Op, ML, O);
  } else {
    fa_mono<<<dim3(NQT * NBH), dim3(256), 0, stream>>>(Q, K, V, O);
  }
}